// Round 2
// baseline (867.951 us; speedup 1.0000x reference)
//
#include <hip/hip_runtime.h>

// Correlation layer: out[b, dh*9+dw, h, w] =
//   (1/196) * sum_c in1[b,c,h,w] * in2[b,c, refl(h+dh-4), refl(w+dw-4)]
// Shapes: in1,in2 = [8,196,128,224] f32 ; out = [8,81,128,224] f32
//
// Round 2: double-buffered LDS (1 barrier/round), register prefetch of BOTH
// in2 staging data and in1 compute data one round ahead, padded LDS row
// stride (236) against bank conflicts.

constexpr int NB = 8, NC = 196, NH = 128, NW = 224;
constexpr int ND = 9;            // displacements per axis
constexpr int PADV = 4;
constexpr int WSP = 236;         // padded staged row stride (floats); data in [0,232)
constexpr int KC = 2;            // channels per round
constexpr int NSLOT = 56;        // w-groups of 4
constexpr int ACTIVE = ND * NSLOT;   // 504 compute threads
constexpr int TPB = 512;
constexpr int HWSZ = NH * NW;    // 28672
constexpr int NROUND = NC / KC;  // 98
constexpr int BUF = KC * ND * WSP;   // floats per LDS buffer (4248)

__device__ __forceinline__ int refl(int v, int n) {
    v = v < 0 ? -v : v;
    return v >= n ? 2 * n - 2 - v : v;
}

__global__ __launch_bounds__(TPB)
void corr_kernel(const float* __restrict__ in1,
                 const float* __restrict__ in2,
                 float* __restrict__ out)
{
    __shared__ __align__(16) float s_win[2 * BUF];   // 33984 B -> 4 blocks/CU

    const int tid = threadIdx.x;
    const int bh  = blockIdx.x;
    const int b   = bh / NH;
    const int h   = bh - b * NH;

    // ---- staging precompute (fixed across rounds) ----
    // Part A: interior float4 slots: KC*ND*56 = 1008, s = 4+4g, x = 4g
    const float* gA[2];
    int  lA[2];
    bool vA[2];
#pragma unroll
    for (int k = 0; k < 2; ++k) {
        int v  = tid + k * TPB;
        vA[k]  = v < KC * ND * NSLOT;
        int vv = vA[k] ? v : 0;
        int cc = vv / (ND * NSLOT);
        int r  = vv - cc * (ND * NSLOT);
        int dh = r / NSLOT;
        int g  = r - dh * NSLOT;
        int y  = refl(h + dh - PADV, NH);
        gA[k]  = in2 + ((b * NC + cc) * NH + y) * NW + 4 * g;
        lA[k]  = (cc * ND + dh) * WSP + 4 + 4 * g;
    }
    // Part B: edge scalars: KC*ND*8 = 144
    const float* gB = in2;
    int  lB = 0;
    const bool vB = tid < KC * ND * 8;
    {
        int v  = vB ? tid : 0;
        int cc = v / (ND * 8);
        int r  = v - cc * (ND * 8);
        int dh = r / 8;
        int e  = r - dh * 8;
        int s  = e < 4 ? e : 224 + e;
        int x  = e < 4 ? 4 - e : 226 - e;
        int y  = refl(h + dh - PADV, NH);
        gB = in2 + ((b * NC + cc) * NH + y) * NW + x;
        lB = (cc * ND + dh) * WSP + s;
    }

    // ---- compute-thread identity ----
    const int  cdh  = tid / NSLOT;          // 0..8
    const int  slot = tid - cdh * NSLOT;    // 0..55
    const int  w0   = slot * 4;
    const bool compute = tid < ACTIVE;
    const float* a1p = in1 + ((b * NC) * NH + h) * NW + w0;

    float acc[ND][4];
#pragma unroll
    for (int d = 0; d < ND; ++d)
#pragma unroll
        for (int p = 0; p < 4; ++p) acc[d][p] = 0.f;

    // ---- preamble: fill buf0 with round 0; prefetch round 1 into regs ----
    float4 sA[2];
    float  sB = 0.f;
#pragma unroll
    for (int k = 0; k < 2; ++k)
        if (vA[k]) sA[k] = *(const float4*)(gA[k]);
    if (vB) sB = gB[0];
#pragma unroll
    for (int k = 0; k < 2; ++k)
        if (vA[k]) *(float4*)&s_win[lA[k]] = sA[k];
    if (vB) s_win[lB] = sB;
    // prefetch in2 for round 1 (channels 2,3)
#pragma unroll
    for (int k = 0; k < 2; ++k)
        if (vA[k]) sA[k] = *(const float4*)(gA[k] + KC * HWSZ);
    if (vB) sB = gB[KC * HWSZ];
    // prefetch in1 for round 0 (channels 0,1)
    float4 iE[2], iO[2];
    if (compute) {
        iE[0] = *(const float4*)(a1p + 0 * HWSZ);
        iE[1] = *(const float4*)(a1p + 1 * HWSZ);
    }
    __syncthreads();

    auto do_compute = [&](const float* base, const float4* iv) {
#pragma unroll
        for (int cc = 0; cc < KC; ++cc) {
            const float* wrow = base + (cc * ND + cdh) * WSP + w0;
            float4 wv0 = *(const float4*)(wrow);
            float4 wv1 = *(const float4*)(wrow + 4);
            float4 wv2 = *(const float4*)(wrow + 8);
            const float wn[12] = {wv0.x, wv0.y, wv0.z, wv0.w,
                                  wv1.x, wv1.y, wv1.z, wv1.w,
                                  wv2.x, wv2.y, wv2.z, wv2.w};
            const float4 a = iv[cc];
#pragma unroll
            for (int d = 0; d < ND; ++d) {
                acc[d][0] += a.x * wn[d + 0];
                acc[d][1] += a.y * wn[d + 1];
                acc[d][2] += a.z * wn[d + 2];
                acc[d][3] += a.w * wn[d + 3];
            }
        }
    };

    for (int r = 0; r < NROUND; r += 2) {
        // ---- round r (even): compute from buf0; regs hold round r+1 data ----
        // write round r+1 staging -> buf1 (nobody reads buf1 this round)
#pragma unroll
        for (int k = 0; k < 2; ++k)
            if (vA[k]) *(float4*)&s_win[BUF + lA[k]] = sA[k];
        if (vB) s_win[BUF + lB] = sB;
        // prefetch in2 for round r+2
        if (r + 2 < NROUND) {
            const int off = (r + 2) * KC * HWSZ;
#pragma unroll
            for (int k = 0; k < 2; ++k)
                if (vA[k]) sA[k] = *(const float4*)(gA[k] + off);
            if (vB) sB = gB[off];
        }
        // prefetch in1 for round r+1
        if (compute) {
            const int c = (r + 1) * KC;
            iO[0] = *(const float4*)(a1p + (c + 0) * HWSZ);
            iO[1] = *(const float4*)(a1p + (c + 1) * HWSZ);
        }
        do_compute(&s_win[0], iE);
        __syncthreads();

        // ---- round r+1 (odd): compute from buf1; regs hold round r+2 data ----
        if (r + 2 < NROUND) {
#pragma unroll
            for (int k = 0; k < 2; ++k)
                if (vA[k]) *(float4*)&s_win[lA[k]] = sA[k];
            if (vB) s_win[lB] = sB;
            // prefetch in2 for round r+3
            if (r + 3 < NROUND) {
                const int off = (r + 3) * KC * HWSZ;
#pragma unroll
                for (int k = 0; k < 2; ++k)
                    if (vA[k]) sA[k] = *(const float4*)(gA[k] + off);
                if (vB) sB = gB[off];
            }
            // prefetch in1 for round r+2
            if (compute) {
                const int c = (r + 2) * KC;
                iE[0] = *(const float4*)(a1p + (c + 0) * HWSZ);
                iE[1] = *(const float4*)(a1p + (c + 1) * HWSZ);
            }
        }
        do_compute(&s_win[BUF], iO);
        __syncthreads();
    }

    if (compute) {
        const float scale = 1.0f / 196.0f;
#pragma unroll
        for (int d = 0; d < ND; ++d) {
            float4 o;
            o.x = acc[d][0] * scale;
            o.y = acc[d][1] * scale;
            o.z = acc[d][2] * scale;
            o.w = acc[d][3] * scale;
            float* op = out + (((b * (ND * ND)) + cdh * ND + d) * NH + h) * NW + w0;
            *(float4*)op = o;
        }
    }
}

extern "C" void kernel_launch(void* const* d_in, const int* in_sizes, int n_in,
                              void* d_out, int out_size, void* d_ws, size_t ws_size,
                              hipStream_t stream)
{
    const float* in1 = (const float*)d_in[0];
    const float* in2 = (const float*)d_in[1];
    float* outp = (float*)d_out;
    dim3 grid(NB * NH);
    dim3 block(TPB);
    hipLaunchKernelGGL(corr_kernel, grid, block, 0, stream, in1, in2, outp);
}